// Round 15
// baseline (109.956 us; speedup 1.0000x reference)
//
#include <hip/hip_runtime.h>

// CRF log-likelihood, MI355X. SEQ=512, B=1024, T=48.
// SEQUENCE-PARALLEL x4: seg s covers t[128s,128(s+1)), warm-up 32 steps from
// uniform state for s>0 (Birkhoff contraction -> fp32-exact; validated R13).
// 4096 waves = 4/SIMD (launch_bounds(64,4) caps VGPR at 128). Linear-domain
// recurrence r <- (r @ E)*exp(e)*2^-6; E=exp(trans) in 48 VGPRs BUILT FROM
// LDS (global builds get rematerialized -> R13's VGPR=52 regression). The
// 9.2 KB ltr LDS is then REUSED as the emission double-buffer (CH=16).
// Exact log-domain stitch: den = B0 + sum_{s>=1}(Bs - Ws), en in B3 only.
// Numerator chunk-parallel per segment; last-tag resolved in reducer.
// R14 fix: no LDS pointer arrays (addrspacecast static-init error) —
// buffer selected by integer offset.

constexpr int SEQ = 512, BN = 1024, TT = 48;
constexpr int CH = 16;
#define LOG2E 1.44269504088896340736f
#define LN2   0.69314718055994530942f

__device__ __forceinline__ float fexp2(float x) { return __builtin_amdgcn_exp2f(x); }
__device__ __forceinline__ float flog2(float x) { return __builtin_amdgcn_logf(x); }
__device__ __forceinline__ float rlane(float v, int i) {
    return __int_as_float(__builtin_amdgcn_readlane(__float_as_int(v), i));
}

__global__ __launch_bounds__(64, 4) void crf_fwd(
    const float* __restrict__ emis, const int* __restrict__ tags,
    const int* __restrict__ mask, const float* __restrict__ start_t,
    const float* __restrict__ end_t, const float* __restrict__ trans,
    float* __restrict__ ws)
{
    __shared__ __align__(16) float smem[TT * TT];  // 9216 B: ltr, then ebuf x2

    const int lane = threadIdx.x;
    const int b   = blockIdx.x & 1023;
    const int seg = blockIdx.x >> 10;        // 0..3
    const int cstart = seg ? (8 * seg - 2) : 0;
    const int cend   = 8 * (seg + 1);

    const bool jv = (lane < TT);
    const int jc = jv ? lane : (TT - 1);
    const int l15 = lane & 15;

    // ---- phase 1: ltr in LDS, build E in VGPRs (no remat possible) ----
    for (int i = lane; i < TT * TT; i += 64) smem[i] = trans[i];
    __syncthreads();
    float E[TT];
#pragma unroll
    for (int i = 0; i < TT; ++i)
        E[i] = fexp2(smem[i * TT + jc] * LOG2E);
#pragma unroll
    for (int i = 0; i < TT; ++i)
        asm volatile("" : "+v"(E[i]));
    const float st = start_t[jc];
    const float en = end_t[jc];
    __syncthreads();

    // ---- phase 2: smem[0..1535] becomes emission double-buffer ----
    int offs[3];
#pragma unroll
    for (int k = 0; k < 3; ++k) {
        const int g = k * 64 + lane;
        const int r = g / 12, j4 = g % 12;
        offs[k] = r * (BN * TT * 4) + j4 * 16;
    }

#define STAGE_CHUNK(cc, buf)                                                   \
    {                                                                          \
        const char* cb = (const char*)emis + ((size_t)(cc) * CH * BN + b) * (TT * 4); \
        _Pragma("unroll")                                                      \
        for (int k = 0; k < 3; ++k) {                                          \
            __builtin_amdgcn_global_load_lds(                                  \
                (const __attribute__((address_space(1))) void*)(cb + offs[k]), \
                (__attribute__((address_space(3))) void*)(&smem[(buf) * (CH * TT) + k * 256]), \
                16, 0, 0);                                                     \
        }                                                                      \
    }

    STAGE_CHUNK(cstart, 0);
    int tgv = tags[(size_t)(cstart * CH + l15) * BN + b];
    int mkv = mask[(size_t)(cstart * CH + l15) * BN + b];

    asm volatile("s_waitcnt vmcnt(0)" ::: "memory");
    __builtin_amdgcn_sched_barrier(0);

    float r, numpart;
    int la, carry_tag;
    if (seg == 0) {
        const int tag0 = tags[b];
        const float e00 = smem[jc];
        r = jv ? fexp2(fmaf(st + e00, LOG2E, -6.0f)) : 0.0f;
        la = 6;
        numpart = (lane == tag0) ? (st + e00) : 0.f;
        carry_tag = tag0;
    } else {
        r = jv ? 1.0f : 0.0f;   // warm-up init (scale cancels in B - W)
        la = 0;
        numpart = 0.f;
        carry_tag = 0;
    }
    float numtr = 0.f, numem = 0.f, W = 0.f;
    int mcount = 0;

    STAGE_CHUNK(cstart + 1, 1);
    int tgn = tags[(size_t)((cstart + 1) * CH + l15) * BN + b];
    int mkn = mask[(size_t)((cstart + 1) * CH + l15) * BN + b];

    int cur = 0;

#pragma unroll 1
    for (int c = cstart; c < cend; ++c) {
        const int tbase = c * CH;
        const float* ebc = smem + cur * (CH * TT);
        const bool warm = (c < 8 * seg);

        // ---- chunk-parallel numerator + commit word (lanes 0..15 = steps) ----
        const int tmv = (lane < 16 && mkv && (tbase + lane) > 0) ? tgv : -1;
        const unsigned long long vmword = __ballot(tmv >= 0);
        int tprev = __shfl_up(tgv, 1, 64);
        if (lane == 0) tprev = carry_tag;
        if (!warm) {
            if (tmv >= 0) {
                numtr += trans[tprev * TT + tgv];   // L1-hot, off-chain
                numem += ebc[lane * TT + tgv];
            }
            mcount += __popcll(__ballot(lane < 16 && mkv));
        }
        carry_tag = __builtin_amdgcn_readlane(tgv, 15);
        la += 6 * (int)__popcll(vmword);

        // group-0 emission rows
        float ev[8];
#pragma unroll
        for (int u = 0; u < 8; ++u) ev[u] = ebc[u * TT + jc];

        // ---- 2 groups x 8 serial steps ----
#pragma unroll 1
        for (int sc = 0; sc < 2; ++sc) {
            float emul[8];
#pragma unroll
            for (int u = 0; u < 8; ++u)
                emul[u] = fexp2(fmaf(ev[u], LOG2E, -6.0f));
            if (sc == 0) {
#pragma unroll
                for (int u = 0; u < 8; ++u)
                    ev[u] = ebc[(8 + u) * TT + jc];
            }
            const unsigned gm = (unsigned)(vmword >> (sc * 8)) & 0xFFu;
            {   // renorm: exact power-of-2 from lane 0's exponent
                const float r0 = rlane(r, 0);
                const int m = ((__float_as_int(r0) >> 23) & 0xFF) - 127;
                const float scl = __int_as_float((127 - m) << 23);
                r *= scl;
                la += m;
            }
#pragma unroll
            for (int u = 0; u < 8; ++u) {
                float q0 = 0.f, q1 = 0.f, q2 = 0.f, q3 = 0.f;
#pragma unroll
                for (int i = 0; i < TT; i += 4) {
                    q0 = fmaf(rlane(r, i),     E[i],     q0);
                    q1 = fmaf(rlane(r, i + 1), E[i + 1], q1);
                    q2 = fmaf(rlane(r, i + 2), E[i + 2], q2);
                    q3 = fmaf(rlane(r, i + 3), E[i + 3], q3);
                }
                const float q = (q0 + q1) + (q2 + q3);
                const bool commit = (gm >> u) & 1u;
                r = commit ? (q * emul[u]) : r;
            }
        }

        // ---- chunk boundary ----
        asm volatile("s_waitcnt vmcnt(0)" ::: "memory");
        __builtin_amdgcn_sched_barrier(0);
        cur ^= 1;
        tgv = tgn; mkv = mkn;
        if (c + 2 < cend) {
            STAGE_CHUNK(c + 2, cur ^ 1);
            tgn = tags[(size_t)((c + 2) * CH + l15) * BN + b];
            mkn = mask[(size_t)((c + 2) * CH + l15) * BN + b];
        }
        if (seg && c == 8 * seg - 1) {  // warm-up done: capture W (la included)
            float sv = jv ? r : 0.f, se = sv;
#pragma unroll
            for (int d = 1; d < 64; d <<= 1)
                se += __shfl_xor(se, d, 64);
            W = (flog2(se) + (float)la) * LN2;
        }
    }

    // ---- tails ----
    float num = numpart + numtr + numem;
#pragma unroll
    for (int d = 1; d < 64; d <<= 1)
        num += __shfl_xor(num, d, 64);

    float sv = jv ? r : 0.f;
    if (seg == 3) sv = jv ? (r * fexp2(en * LOG2E)) : 0.f;
    float se = sv;
#pragma unroll
    for (int d = 1; d < 64; d <<= 1)
        se += __shfl_xor(se, d, 64);
    const float B = (flog2(se) + (float)la) * LN2;

    if (lane == 0) {
        ws[seg * 1024 + b]          = num;
        ws[4096 + seg * 1024 + b]   = B;
        ws[8192 + seg * 1024 + b]   = W;       // 0 for seg 0
        ws[12288 + seg * 1024 + b]  = (float)mcount;
    }
#undef STAGE_CHUNK
}

__global__ __launch_bounds__(256) void reduce_mean(
    const float* __restrict__ ws, const int* __restrict__ tags,
    const float* __restrict__ end_t, float* __restrict__ out)
{
    const int tid = threadIdx.x;
    float v = 0.f;
#pragma unroll
    for (int k = 0; k < 4; ++k) {
        const int b = tid + 256 * k;
        float num = 0.f, den = 0.f, mcf = 0.f;
#pragma unroll
        for (int s = 0; s < 4; ++s) {
            num += ws[s * 1024 + b];
            den += ws[4096 + s * 1024 + b] - ws[8192 + s * 1024 + b];
            mcf += ws[12288 + s * 1024 + b];
        }
        const int mc = (int)mcf;
        const int lt = tags[(size_t)(mc - 1) * BN + b];
        v += num + end_t[lt] - den;
    }
#pragma unroll
    for (int d = 1; d < 64; d <<= 1)
        v += __shfl_xor(v, d, 64);
    __shared__ float acc[4];
    if ((tid & 63) == 0) acc[tid >> 6] = v;
    __syncthreads();
    if (tid == 0) out[0] = (acc[0] + acc[1] + acc[2] + acc[3]) * (1.f / 1024.f);
}

extern "C" void kernel_launch(void* const* d_in, const int* in_sizes, int n_in,
                              void* d_out, int out_size, void* d_ws, size_t ws_size,
                              hipStream_t stream)
{
    const float* emis    = (const float*)d_in[0];
    const int*   tags    = (const int*)d_in[1];
    const int*   mask    = (const int*)d_in[2];
    const float* start_t = (const float*)d_in[3];
    const float* end_t   = (const float*)d_in[4];
    const float* trans   = (const float*)d_in[5];
    float* ws  = (float*)d_ws;
    float* out = (float*)d_out;

    crf_fwd<<<dim3(4096), dim3(64), 0, stream>>>(emis, tags, mask, start_t, end_t, trans, ws);
    reduce_mean<<<dim3(1), dim3(256), 0, stream>>>(ws, tags, end_t, out);
}

// Round 16
// 82.695 us; speedup vs baseline: 1.3296x; 1.3296x over previous
//
#include <hip/hip_runtime.h>

// CRF log-likelihood, MI355X. SEQ=512, B=1024, T=48.
// SEQUENCE-PARALLEL x4 (R15 structure): seg s covers t[128s,128(s+1)),
// 16-step warm-up from uniform state for s>0 (Birkhoff contraction 0.1/step,
// emission diagonals are Hilbert isometries -> fp32-exact stitch; 32-step
// version validated absmax 0.0 in R13/R15). Linear-domain recurrence
// r <- (r @ E) * exp(e)*2^-6 with the matvec in PACKED F16 DOT2:
// E = exp(trans) as 24 packed-f16 VGPRs, p packed per step via DPP quad-swap
// + cvt_pkrtz (even lanes valid), 24 readlane + 24 v_dot2_f32_f16.
// launch_bounds(64,1): no VGPR cap -> no scratch spill (R15's VGPR=52 bug was
// the (64,4) cap making the allocator spill E). Exact power-of-2 renorm per
// 8-step group; integer log2 bookkeeping; exact log-domain stitch
// den = B0 + sum_{s>=1}(Bs - Ws). Numerator chunk-parallel per segment.

constexpr int SEQ = 512, BN = 1024, TT = 48;
constexpr int CH = 16;
#define LOG2E 1.44269504088896340736f
#define LN2   0.69314718055994530942f

typedef _Float16 h16x2 __attribute__((ext_vector_type(2)));

__device__ __forceinline__ float fexp2(float x) { return __builtin_amdgcn_exp2f(x); }
__device__ __forceinline__ float flog2(float x) { return __builtin_amdgcn_logf(x); }
__device__ __forceinline__ float rlane(float v, int i) {
    return __int_as_float(__builtin_amdgcn_readlane(__float_as_int(v), i));
}
__device__ __forceinline__ float dppswap(float v) {  // lane ^= 1 (quad_perm [1,0,3,2])
    return __int_as_float(__builtin_amdgcn_mov_dpp(__float_as_int(v), 0xB1, 0xF, 0xF, true));
}
__device__ __forceinline__ float fdot2(int a, int b, float c) {
#if __has_builtin(__builtin_amdgcn_fdot2)
    return __builtin_amdgcn_fdot2(__builtin_bit_cast(h16x2, a),
                                  __builtin_bit_cast(h16x2, b), c, false);
#else
    float r;
    asm("v_dot2_f32_f16 %0, %1, %2, %3" : "=v"(r) : "v"(a), "v"(b), "v"(c));
    return r;
#endif
}

__global__ __launch_bounds__(64, 1) void crf_fwd(
    const float* __restrict__ emis, const int* __restrict__ tags,
    const int* __restrict__ mask, const float* __restrict__ start_t,
    const float* __restrict__ end_t, const float* __restrict__ trans,
    float* __restrict__ ws)
{
    __shared__ __align__(16) float smem[TT * TT];  // 9216 B: ltr, then ebuf x2

    const int lane = threadIdx.x;
    const int b   = blockIdx.x & 1023;
    const int seg = blockIdx.x >> 10;        // 0..3
    const int cstart = seg ? (8 * seg - 1) : 0;   // 1 warm-up chunk (16 steps)
    const int cend   = 8 * (seg + 1);

    const bool jv = (lane < TT);
    const int jc = jv ? lane : (TT - 1);
    const int l15 = lane & 15;

    // ---- phase 1: ltr in LDS, build packed-f16 E in 24 VGPRs ----
    for (int i = lane; i < TT * TT; i += 64) smem[i] = trans[i];
    __syncthreads();
    int Epk[24];
#pragma unroll
    for (int k = 0; k < 24; ++k) {
        const float a = fexp2(smem[(2 * k) * TT + jc] * LOG2E);
        const float bb = fexp2(smem[(2 * k + 1) * TT + jc] * LOG2E);
        h16x2 hv = { (_Float16)a, (_Float16)bb };
        Epk[k] = __builtin_bit_cast(int, hv);
    }
#pragma unroll
    for (int k = 0; k < 24; ++k)
        asm volatile("" : "+v"(Epk[k]));
    const float st = start_t[jc];
    const float en = end_t[jc];
    __syncthreads();

    // ---- phase 2: smem[0..1535] becomes emission double-buffer ----
    int offs[3];
#pragma unroll
    for (int k = 0; k < 3; ++k) {
        const int g = k * 64 + lane;
        const int r = g / 12, j4 = g % 12;
        offs[k] = r * (BN * TT * 4) + j4 * 16;
    }

#define STAGE_CHUNK(cc, buf)                                                   \
    {                                                                          \
        const char* cb = (const char*)emis + ((size_t)(cc) * CH * BN + b) * (TT * 4); \
        _Pragma("unroll")                                                      \
        for (int k = 0; k < 3; ++k) {                                          \
            __builtin_amdgcn_global_load_lds(                                  \
                (const __attribute__((address_space(1))) void*)(cb + offs[k]), \
                (__attribute__((address_space(3))) void*)(&smem[(buf) * (CH * TT) + k * 256]), \
                16, 0, 0);                                                     \
        }                                                                      \
    }

    STAGE_CHUNK(cstart, 0);
    int tgv = tags[(size_t)(cstart * CH + l15) * BN + b];
    int mkv = mask[(size_t)(cstart * CH + l15) * BN + b];

    asm volatile("s_waitcnt vmcnt(0)" ::: "memory");
    __builtin_amdgcn_sched_barrier(0);

    float r, numpart;
    int la, carry_tag;
    if (seg == 0) {
        const int tag0 = tags[b];
        const float e00 = smem[jc];
        r = jv ? fexp2(fmaf(st + e00, LOG2E, -6.0f)) : 0.0f;
        la = 6;
        numpart = (lane == tag0) ? (st + e00) : 0.f;
        carry_tag = tag0;
    } else {
        r = jv ? 1.0f : 0.0f;   // warm-up init (scale cancels in B - W)
        la = 0;
        numpart = 0.f;
        carry_tag = 0;
    }
    float numtr = 0.f, numem = 0.f, W = 0.f;
    int mcount = 0;

    STAGE_CHUNK(cstart + 1, 1);
    int tgn = tags[(size_t)((cstart + 1) * CH + l15) * BN + b];
    int mkn = mask[(size_t)((cstart + 1) * CH + l15) * BN + b];

    int cur = 0;

#pragma unroll 1
    for (int c = cstart; c < cend; ++c) {
        const int tbase = c * CH;
        const float* ebc = smem + cur * (CH * TT);
        const bool warm = (c < 8 * seg);

        // ---- chunk-parallel numerator + commit word (lanes 0..15 = steps) ----
        const int tmv = (lane < 16 && mkv && (tbase + lane) > 0) ? tgv : -1;
        const unsigned long long vmword = __ballot(tmv >= 0);
        int tprev = __shfl_up(tgv, 1, 64);
        if (lane == 0) tprev = carry_tag;
        if (!warm) {
            if (tmv >= 0) {
                numtr += trans[tprev * TT + tgv];   // L1-hot, off-chain
                numem += ebc[lane * TT + tgv];
            }
            mcount += __popcll(__ballot(lane < 16 && mkv));
        }
        carry_tag = __builtin_amdgcn_readlane(tgv, 15);
        la += 6 * (int)__popcll(vmword);

        // group-0 emission rows
        float ev[8];
#pragma unroll
        for (int u = 0; u < 8; ++u) ev[u] = ebc[u * TT + jc];

        // ---- 2 groups x 8 serial steps ----
#pragma unroll 1
        for (int sc = 0; sc < 2; ++sc) {
            float emul[8];
#pragma unroll
            for (int u = 0; u < 8; ++u)
                emul[u] = fexp2(fmaf(ev[u], LOG2E, -6.0f));
            if (sc == 0) {
#pragma unroll
                for (int u = 0; u < 8; ++u)
                    ev[u] = ebc[(8 + u) * TT + jc];
            }
            const unsigned gm = (unsigned)(vmword >> (sc * 8)) & 0xFFu;
            {   // renorm: exact power-of-2 from lane 0's exponent
                const float r0 = rlane(r, 0);
                const int m = ((__float_as_int(r0) >> 23) & 0xFF) - 127;
                const float scl = __int_as_float((127 - m) << 23);
                r *= scl;
                la += m;
            }
#pragma unroll
            for (int u = 0; u < 8; ++u) {
                // pack (r_2k, r_2k+1) on even lanes; odd-lane pk unused
                const float rx = dppswap(r);
                const int pkw = __builtin_bit_cast(int,
                    __builtin_amdgcn_cvt_pkrtz(r, rx));
                float q0 = 0.f, q1 = 0.f, q2 = 0.f, q3 = 0.f;
#pragma unroll
                for (int k = 0; k < 24; k += 4) {
                    const int p0 = __builtin_amdgcn_readlane(pkw, 2 * k);
                    const int p1 = __builtin_amdgcn_readlane(pkw, 2 * k + 2);
                    const int p2 = __builtin_amdgcn_readlane(pkw, 2 * k + 4);
                    const int p3 = __builtin_amdgcn_readlane(pkw, 2 * k + 6);
                    q0 = fdot2(p0, Epk[k],     q0);
                    q1 = fdot2(p1, Epk[k + 1], q1);
                    q2 = fdot2(p2, Epk[k + 2], q2);
                    q3 = fdot2(p3, Epk[k + 3], q3);
                }
                const float q = (q0 + q1) + (q2 + q3);
                const bool commit = (gm >> u) & 1u;
                r = commit ? (q * emul[u]) : r;
            }
        }

        // ---- chunk boundary ----
        asm volatile("s_waitcnt vmcnt(0)" ::: "memory");
        __builtin_amdgcn_sched_barrier(0);
        cur ^= 1;
        tgv = tgn; mkv = mkn;
        if (c + 2 < cend) {
            STAGE_CHUNK(c + 2, cur ^ 1);
            tgn = tags[(size_t)((c + 2) * CH + l15) * BN + b];
            mkn = mask[(size_t)((c + 2) * CH + l15) * BN + b];
        }
        if (seg && c == 8 * seg - 1) {  // warm-up done: capture W (la included)
            float sv = jv ? r : 0.f, se = sv;
#pragma unroll
            for (int d = 1; d < 64; d <<= 1)
                se += __shfl_xor(se, d, 64);
            W = (flog2(se) + (float)la) * LN2;
        }
    }

    // ---- tails ----
    float num = numpart + numtr + numem;
#pragma unroll
    for (int d = 1; d < 64; d <<= 1)
        num += __shfl_xor(num, d, 64);

    float sv = jv ? r : 0.f;
    if (seg == 3) sv = jv ? (r * fexp2(en * LOG2E)) : 0.f;
    float se = sv;
#pragma unroll
    for (int d = 1; d < 64; d <<= 1)
        se += __shfl_xor(se, d, 64);
    const float B = (flog2(se) + (float)la) * LN2;

    if (lane == 0) {
        ws[seg * 1024 + b]          = num;
        ws[4096 + seg * 1024 + b]   = B;
        ws[8192 + seg * 1024 + b]   = W;       // 0 for seg 0
        ws[12288 + seg * 1024 + b]  = (float)mcount;
    }
#undef STAGE_CHUNK
}

__global__ __launch_bounds__(256) void reduce_mean(
    const float* __restrict__ ws, const int* __restrict__ tags,
    const float* __restrict__ end_t, float* __restrict__ out)
{
    const int tid = threadIdx.x;
    float v = 0.f;
#pragma unroll
    for (int k = 0; k < 4; ++k) {
        const int b = tid + 256 * k;
        float num = 0.f, den = 0.f, mcf = 0.f;
#pragma unroll
        for (int s = 0; s < 4; ++s) {
            num += ws[s * 1024 + b];
            den += ws[4096 + s * 1024 + b] - ws[8192 + s * 1024 + b];
            mcf += ws[12288 + s * 1024 + b];
        }
        const int mc = (int)mcf;
        const int lt = tags[(size_t)(mc - 1) * BN + b];
        v += num + end_t[lt] - den;
    }
#pragma unroll
    for (int d = 1; d < 64; d <<= 1)
        v += __shfl_xor(v, d, 64);
    __shared__ float acc[4];
    if ((tid & 63) == 0) acc[tid >> 6] = v;
    __syncthreads();
    if (tid == 0) out[0] = (acc[0] + acc[1] + acc[2] + acc[3]) * (1.f / 1024.f);
}

extern "C" void kernel_launch(void* const* d_in, const int* in_sizes, int n_in,
                              void* d_out, int out_size, void* d_ws, size_t ws_size,
                              hipStream_t stream)
{
    const float* emis    = (const float*)d_in[0];
    const int*   tags    = (const int*)d_in[1];
    const int*   mask    = (const int*)d_in[2];
    const float* start_t = (const float*)d_in[3];
    const float* end_t   = (const float*)d_in[4];
    const float* trans   = (const float*)d_in[5];
    float* ws  = (float*)d_ws;
    float* out = (float*)d_out;

    crf_fwd<<<dim3(4096), dim3(64), 0, stream>>>(emis, tags, mask, start_t, end_t, trans, ws);
    reduce_mean<<<dim3(1), dim3(256), 0, stream>>>(ws, tags, end_t, out);
}